// Round 12
// baseline (91.564 us; speedup 1.0000x reference)
//
#include <hip/hip_runtime.h>
#include <hip/hip_fp16.h>

#define N_NODES 50000
#define N_EDGES 1600000
#define IN_CH   128
#define NEG     0.2f
#define NBUK    391      // buckets of 128 node-ids: bucket = dst >> 7
#define BCAP    4608     // per-bucket edge capacity (mean 4096, +8 sigma)
#define CAP     80       // per-node list capacity (mean deg 32, +8.5 sigma)
#define CHUNK   2048
#define P_BLOCKS 782     // ceil(E / CHUNK)
#define PT      512      // partition threads

// ---------------- GEMM h = x @ W (+ fused attention logits) ------------------
// 4 threads/row (16 cols each). Output hI is HEAD-INTERLEAVED:
// hI[row*32 + c] = u32( f16 h[row][c] , f16 h[row][32+c] )  (lo=head0, hi=head1)
// Block 0 also zeroes gcur (replaces a fillBuffer dispatch).
__global__ __launch_bounds__(256) void gemm_logits(
    const float* __restrict__ x, const float* __restrict__ W,
    const float* __restrict__ att_src, const float* __restrict__ att_dst,
    unsigned int* __restrict__ hI, float* __restrict__ as_, float* __restrict__ ad_,
    int* __restrict__ gcur)
{
    if (blockIdx.x == 0) {
        for (int i = threadIdx.x; i < NBUK; i += 256) gcur[i] = 0;
    }

    __shared__ float Wl[IN_CH * 64];
    for (int i = threadIdx.x; i < IN_CH * 64; i += 256) Wl[i] = W[i];
    __syncthreads();

    int gid = blockIdx.x * 256 + threadIdx.x;
    int row = gid >> 2;
    int sub = gid & 3;            // 16-col slice; head = sub>>1
    if (row >= N_NODES) return;

    float acc[16];
#pragma unroll
    for (int c = 0; c < 16; ++c) acc[c] = 0.f;

    const float* xr = x + (size_t)row * IN_CH;
    for (int k = 0; k < IN_CH; k += 4) {
        float4 xv = *(const float4*)(xr + k);
        float xs[4] = {xv.x, xv.y, xv.z, xv.w};
#pragma unroll
        for (int kk = 0; kk < 4; ++kk) {
            const float* wr = &Wl[(k + kk) * 64 + sub * 16];
#pragma unroll
            for (int c = 0; c < 16; c += 4) {
                float4 wv = *(const float4*)(wr + c);
                acc[c]     += xs[kk] * wv.x;
                acc[c + 1] += xs[kk] * wv.y;
                acc[c + 2] += xs[kk] * wv.z;
                acc[c + 3] += xs[kk] * wv.w;
            }
        }
    }

    // exchange with partner (sub^2): head0 thread gets head1 values
    float part[16];
#pragma unroll
    for (int i = 0; i < 16; ++i) part[i] = __shfl_xor(acc[i], 2);

    if (sub < 2) {   // head0 owner: pack (h0, h1) pairs for cols sub*16+i
        union { unsigned int u[16]; uint4 v4[4]; } pk;
#pragma unroll
        for (int i = 0; i < 16; ++i) {
            pk.u[i] = (unsigned)__half_as_ushort(__float2half_rn(acc[i])) |
                      ((unsigned)__half_as_ushort(__float2half_rn(part[i])) << 16);
        }
        uint4* hp = (uint4*)(hI + (size_t)row * 32 + sub * 16);
#pragma unroll
        for (int i = 0; i < 4; ++i) hp[i] = pk.v4[i];
    }

    float s = 0.f, d = 0.f;
#pragma unroll
    for (int c = 0; c < 16; ++c) {
        s += acc[c] * att_src[sub * 16 + c];
        d += acc[c] * att_dst[sub * 16 + c];
    }
    s += __shfl_xor(s, 1);
    d += __shfl_xor(d, 1);
    if ((sub & 1) == 0) {
        as_[row * 2 + (sub >> 1)] = s;
        ad_[row * 2 + (sub >> 1)] = d;
    }
}

// ---------------- LDS-staged radix partition (register-cached edges) ---------
// 2048 edges/block (one int4 per thread), 782 blocks for CU balance.
// Packed word: src(16) | dstlow(7)<<16 | bucket(9)<<23.
__global__ __launch_bounds__(PT) void partition(
    const int* __restrict__ ei, int* __restrict__ gcur,
    unsigned int* __restrict__ barr)
{
    __shared__ int hist[NBUK];
    __shared__ int start[NBUK];
    __shared__ int gbase[NBUK];
    __shared__ int lofs[NBUK];
    __shared__ int wsum[8];
    __shared__ int woff[8];
    __shared__ unsigned int buf[CHUNK];

    int tid = threadIdx.x;
    int lane = tid & 63, wid = tid >> 6;
    int cbase = blockIdx.x * CHUNK;
    int cnt = N_EDGES - cbase;
    if (cnt > CHUNK) cnt = CHUNK;
    int n4 = cnt >> 2;                        // cnt always divisible by 4

    for (int i = tid; i < NBUK; i += PT) { hist[i] = 0; lofs[i] = 0; }
    __syncthreads();

    const int4* s4 = (const int4*)ei + (cbase >> 2);
    const int4* d4 = (const int4*)(ei + N_EDGES) + (cbase >> 2);

    // load edges ONCE into registers; histogram as we go
    int4 dv, sv;
    bool have = (tid < n4);
    if (have) {
        dv = d4[tid]; sv = s4[tid];
        atomicAdd(&hist[dv.x >> 7], 1);
        atomicAdd(&hist[dv.y >> 7], 1);
        atomicAdd(&hist[dv.z >> 7], 1);
        atomicAdd(&hist[dv.w >> 7], 1);
    }
    __syncthreads();

    // wave-shfl inclusive scan over NBUK (padded to 512)
    int a = (tid < NBUK) ? hist[tid] : 0;
    int orig = a;
#pragma unroll
    for (int off = 1; off < 64; off <<= 1) {
        int u = __shfl_up(a, off);
        if (lane >= off) a += u;
    }
    if (lane == 63) wsum[wid] = a;
    __syncthreads();
    if (tid == 0) {
        int r = 0;
#pragma unroll
        for (int w = 0; w < 8; ++w) { woff[w] = r; r += wsum[w]; }
    }
    __syncthreads();
    a += woff[wid];
    if (tid < NBUK) {
        start[tid] = a - orig;                              // exclusive
        gbase[tid] = atomicAdd(&gcur[tid], orig);           // reserve global span
    }
    __syncthreads();

    // reorder from registers into LDS by bucket
    if (have) {
        int dd[4] = {dv.x, dv.y, dv.z, dv.w};
        int ss[4] = {sv.x, sv.y, sv.z, sv.w};
#pragma unroll
        for (int e = 0; e < 4; ++e) {
            int d = dd[e];
            int bkt = d >> 7;
            int loc = atomicAdd(&lofs[bkt], 1);
            buf[start[bkt] + loc] =
                (unsigned)ss[e] | ((unsigned)(d & 127) << 16) | ((unsigned)bkt << 23);
        }
    }
    __syncthreads();

    // coalesced flush
    for (int i = tid; i < cnt; i += PT) {
        unsigned u = buf[i];
        int bkt = u >> 23;
        int g = gbase[bkt] + (i - start[bkt]);
        if (g < BCAP) barr[(size_t)bkt * BCAP + g] = u & 0x7FFFFFu;
    }
}

// ---------------- merged order + aggregation, half-bucket blocks -------------
// 2 blocks per bucket, 512 threads (8 waves). Phase 1: scan the bucket's
// entries, demux THIS block's 64 nodes into LDS lists. Phase 2: 2 nodes/wave
// (half-wave each; lane c owns (head0,c)+(head1,c) via head-interleaved hI);
// per edge 1 dword gather serves both heads.
__global__ __launch_bounds__(512) void aggregate(
    const unsigned int* __restrict__ hI, const float* __restrict__ as_,
    const float* __restrict__ ad_, const int* __restrict__ gcur,
    const unsigned int* __restrict__ barr, const float* __restrict__ bias,
    float* __restrict__ out)
{
    __shared__ unsigned short lcol[64 * CAP];   // 10.2 KB
    __shared__ int hist[64];

    int b    = blockIdx.x >> 1;
    int jbase = (blockIdx.x & 1) << 6;          // 0 or 64
    int tid  = threadIdx.x;
    if (tid < 64) hist[tid] = 0;
    __syncthreads();

    int cnt = gcur[b];
    if (cnt > BCAP) cnt = BCAP;
    const unsigned int* bb = barr + (size_t)b * BCAP;

    for (int i = tid; i < cnt; i += 512) {
        unsigned u = bb[i];
        int r = ((int)(u >> 16) & 127) - jbase;
        if ((unsigned)r < 64u) {
            int k = atomicAdd(&hist[r], 1);
            if (k < CAP) lcol[r * CAP + k] = (unsigned short)(u & 0xFFFFu);
        }
    }
    __syncthreads();

    int lane = tid & 63;
    int wave = tid >> 6;                 // 0..7
    int c    = lane & 31;
    int hv   = lane >> 5;                // which node of the wave's pair
    int sl   = lane & 32;                // shuffle source-half base
    float bi0 = bias[c], bi1 = bias[32 + c];

    for (int pass = 0; pass < 4; ++pass) {
        int r = pass * 16 + (wave << 1) + hv;
        int node = b * 128 + jbase + r;
        bool valid = (node < N_NODES);

        float2 adv = valid ? *(const float2*)(ad_ + node * 2) : make_float2(0.f, 0.f);
        float2 asv = valid ? *(const float2*)(as_ + node * 2) : make_float2(0.f, 0.f);

        // self-loop
        float t0 = asv.x + adv.x, t1 = asv.y + adv.y;
        float e0 = (t0 > 0.f) ? t0 : NEG * t0;
        float e1 = (t1 > 0.f) ? t1 : NEG * t1;
        float p0s = __expf(e0), p1s = __expf(e1);
        unsigned hs = valid ? hI[(unsigned)node * 32u + c] : 0u;
        float h0s = __half2float(__ushort_as_half((unsigned short)(hs & 0xFFFFu)));
        float h1s = __half2float(__ushort_as_half((unsigned short)(hs >> 16)));
        float acc0a = p0s * h0s, acc0b = 0.f;
        float acc1a = p1s * h1s, acc1b = 0.f;
        float s0 = 0.f, s1 = 0.f;

        int n = valid ? min(hist[r], CAP) : 0;
        const unsigned short* cb = &lcol[r * CAP];
        int nmax = max(n, __shfl_xor(n, 32));

        for (int base = 0; base < nmax; base += 32) {
            unsigned pack1 = 0, pack2 = 0;
            int myidx = base + c;
            if (myidx < n) {
                int msrc = (int)cb[myidx];
                float2 av = *(const float2*)(as_ + msrc * 2);
                float u0 = av.x + adv.x, u1 = av.y + adv.y;
                float f0 = (u0 > 0.f) ? u0 : NEG * u0;
                float f1 = (u1 > 0.f) ? u1 : NEG * u1;
                float q0 = __expf(f0), q1 = __expf(f1);
                s0 += q0; s1 += q1;
                pack1 = ((unsigned)msrc << 16) |
                        (unsigned)__half_as_ushort(__float2half_rn(q0));
                pack2 = (unsigned)__half_as_ushort(__float2half_rn(q1));
            }
            int c32 = nmax - base;
            if (c32 > 32) c32 = 32;

            int jj = 0;
            for (; jj + 4 <= c32; jj += 4) {
                unsigned aA = __shfl(pack1, sl + jj);
                unsigned bA = __shfl(pack2, sl + jj);
                unsigned aB = __shfl(pack1, sl + jj + 1);
                unsigned bB = __shfl(pack2, sl + jj + 1);
                unsigned aC = __shfl(pack1, sl + jj + 2);
                unsigned bC = __shfl(pack2, sl + jj + 2);
                unsigned aD = __shfl(pack1, sl + jj + 3);
                unsigned bD = __shfl(pack2, sl + jj + 3);
                unsigned vA = hI[(aA >> 16) * 32u + c];
                unsigned vB = hI[(aB >> 16) * 32u + c];
                unsigned vC = hI[(aC >> 16) * 32u + c];
                unsigned vD = hI[(aD >> 16) * 32u + c];
                float pA0 = __half2float(__ushort_as_half((unsigned short)aA));
                float pA1 = __half2float(__ushort_as_half((unsigned short)bA));
                float pB0 = __half2float(__ushort_as_half((unsigned short)aB));
                float pB1 = __half2float(__ushort_as_half((unsigned short)bB));
                float pC0 = __half2float(__ushort_as_half((unsigned short)aC));
                float pC1 = __half2float(__ushort_as_half((unsigned short)bC));
                float pD0 = __half2float(__ushort_as_half((unsigned short)aD));
                float pD1 = __half2float(__ushort_as_half((unsigned short)bD));
                acc0a = fmaf(pA0, __half2float(__ushort_as_half((unsigned short)(vA & 0xFFFFu))), acc0a);
                acc1a = fmaf(pA1, __half2float(__ushort_as_half((unsigned short)(vA >> 16))), acc1a);
                acc0b = fmaf(pB0, __half2float(__ushort_as_half((unsigned short)(vB & 0xFFFFu))), acc0b);
                acc1b = fmaf(pB1, __half2float(__ushort_as_half((unsigned short)(vB >> 16))), acc1b);
                acc0a = fmaf(pC0, __half2float(__ushort_as_half((unsigned short)(vC & 0xFFFFu))), acc0a);
                acc1a = fmaf(pC1, __half2float(__ushort_as_half((unsigned short)(vC >> 16))), acc1a);
                acc0b = fmaf(pD0, __half2float(__ushort_as_half((unsigned short)(vD & 0xFFFFu))), acc0b);
                acc1b = fmaf(pD1, __half2float(__ushort_as_half((unsigned short)(vD >> 16))), acc1b);
            }
            for (; jj < c32; ++jj) {
                unsigned aA = __shfl(pack1, sl + jj);
                unsigned bA = __shfl(pack2, sl + jj);
                unsigned vA = hI[(aA >> 16) * 32u + c];
                float pA0 = __half2float(__ushort_as_half((unsigned short)aA));
                float pA1 = __half2float(__ushort_as_half((unsigned short)bA));
                acc0a = fmaf(pA0, __half2float(__ushort_as_half((unsigned short)(vA & 0xFFFFu))), acc0a);
                acc1a = fmaf(pA1, __half2float(__ushort_as_half((unsigned short)(vA >> 16))), acc1a);
            }
        }

        // reduce denominators within the half-wave (xor <= 16 stays inside)
        s0 += __shfl_xor(s0, 16); s1 += __shfl_xor(s1, 16);
        s0 += __shfl_xor(s0, 8);  s1 += __shfl_xor(s1, 8);
        s0 += __shfl_xor(s0, 4);  s1 += __shfl_xor(s1, 4);
        s0 += __shfl_xor(s0, 2);  s1 += __shfl_xor(s1, 2);
        s0 += __shfl_xor(s0, 1);  s1 += __shfl_xor(s1, 1);
        s0 += p0s; s1 += p1s;

        if (valid) {
            out[(size_t)node * 64 + c]      = (acc0a + acc0b) / s0 + bi0;
            out[(size_t)node * 64 + 32 + c] = (acc1a + acc1b) / s1 + bi1;
        }
    }
}

extern "C" void kernel_launch(void* const* d_in, const int* in_sizes, int n_in,
                              void* d_out, int out_size, void* d_ws, size_t ws_size,
                              hipStream_t stream)
{
    const float* x       = (const float*)d_in[0];
    const int*   ei      = (const int*)d_in[1];
    const float* W       = (const float*)d_in[2];
    const float* att_src = (const float*)d_in[3];
    const float* att_dst = (const float*)d_in[4];
    const float* bias    = (const float*)d_in[5];
    float* out = (float*)d_out;

    char* ws = (char*)d_ws;
    size_t off = 0;
    auto alloc = [&](size_t bytes) -> void* {
        void* p = ws + off;
        off = (off + bytes + 511) & ~(size_t)511;
        return p;
    };
    unsigned int* hI  = (unsigned int*)alloc((size_t)N_NODES * 32 * 4);
    float*  as_ = (float*)alloc((size_t)N_NODES * 2 * 4);
    float*  ad_ = (float*)alloc((size_t)N_NODES * 2 * 4);
    int*    gcur = (int*)alloc((size_t)NBUK * 4);
    unsigned int* barr = (unsigned int*)alloc((size_t)NBUK * BCAP * 4);

    gemm_logits<<<(N_NODES * 4 + 255) / 256, 256, 0, stream>>>(
        x, W, att_src, att_dst, hI, as_, ad_, gcur);
    partition<<<P_BLOCKS, PT, 0, stream>>>(ei, gcur, barr);
    aggregate<<<NBUK * 2, 512, 0, stream>>>(hI, as_, ad_, gcur, barr, bias, out);
}

// Round 13
// 83.146 us; speedup vs baseline: 1.1012x; 1.1012x over previous
//
#include <hip/hip_runtime.h>
#include <hip/hip_fp16.h>

#define N_NODES 50000
#define N_EDGES 1600000
#define IN_CH   128
#define NEG     0.2f
#define NBUK    391      // buckets of 128 node-ids: bucket = dst >> 7
#define BCAP    4608     // per-bucket edge capacity (mean 4096, +8 sigma)
#define CAP     80       // per-node list capacity (mean deg 32, +8.5 sigma)
#define CHUNK   4096
#define P_BLOCKS 391     // ceil(E / CHUNK)
#define PT      512      // partition threads

static __device__ __forceinline__ __half2 u2h2(unsigned u) {
    union { unsigned u; __half2 h; } x; x.u = u; return x.h;
}

// ---------------- GEMM h = x @ W (+ fused attention logits) ------------------
// 4 threads/row (16 cols each). Output hI is HEAD-INTERLEAVED:
// hI[row*32 + c] = u32( f16 h[row][c] , f16 h[row][32+c] )  (lo=head0, hi=head1)
// Block 0 also zeroes gcur (replaces a fillBuffer dispatch).
__global__ __launch_bounds__(256) void gemm_logits(
    const float* __restrict__ x, const float* __restrict__ W,
    const float* __restrict__ att_src, const float* __restrict__ att_dst,
    unsigned int* __restrict__ hI, float* __restrict__ as_, float* __restrict__ ad_,
    int* __restrict__ gcur)
{
    if (blockIdx.x == 0) {
        for (int i = threadIdx.x; i < NBUK; i += 256) gcur[i] = 0;
    }

    __shared__ float Wl[IN_CH * 64];
    for (int i = threadIdx.x; i < IN_CH * 64; i += 256) Wl[i] = W[i];
    __syncthreads();

    int gid = blockIdx.x * 256 + threadIdx.x;
    int row = gid >> 2;
    int sub = gid & 3;            // 16-col slice; head = sub>>1
    if (row >= N_NODES) return;

    float acc[16];
#pragma unroll
    for (int c = 0; c < 16; ++c) acc[c] = 0.f;

    const float* xr = x + (size_t)row * IN_CH;
    for (int k = 0; k < IN_CH; k += 4) {
        float4 xv = *(const float4*)(xr + k);
        float xs[4] = {xv.x, xv.y, xv.z, xv.w};
#pragma unroll
        for (int kk = 0; kk < 4; ++kk) {
            const float* wr = &Wl[(k + kk) * 64 + sub * 16];
#pragma unroll
            for (int c = 0; c < 16; c += 4) {
                float4 wv = *(const float4*)(wr + c);
                acc[c]     += xs[kk] * wv.x;
                acc[c + 1] += xs[kk] * wv.y;
                acc[c + 2] += xs[kk] * wv.z;
                acc[c + 3] += xs[kk] * wv.w;
            }
        }
    }

    // exchange with partner (sub^2): head0 thread gets head1 values
    float part[16];
#pragma unroll
    for (int i = 0; i < 16; ++i) part[i] = __shfl_xor(acc[i], 2);

    if (sub < 2) {   // head0 owner: pack (h0, h1) pairs for cols sub*16+i
        union { unsigned int u[16]; uint4 v4[4]; } pk;
#pragma unroll
        for (int i = 0; i < 16; ++i) {
            pk.u[i] = (unsigned)__half_as_ushort(__float2half_rn(acc[i])) |
                      ((unsigned)__half_as_ushort(__float2half_rn(part[i])) << 16);
        }
        uint4* hp = (uint4*)(hI + (size_t)row * 32 + sub * 16);
#pragma unroll
        for (int i = 0; i < 4; ++i) hp[i] = pk.v4[i];
    }

    float s = 0.f, d = 0.f;
#pragma unroll
    for (int c = 0; c < 16; ++c) {
        s += acc[c] * att_src[sub * 16 + c];
        d += acc[c] * att_dst[sub * 16 + c];
    }
    s += __shfl_xor(s, 1);
    d += __shfl_xor(d, 1);
    if ((sub & 1) == 0) {
        as_[row * 2 + (sub >> 1)] = s;
        ad_[row * 2 + (sub >> 1)] = d;
    }
}

// ---------------- LDS-staged radix partition (register-cached edges) ---------
// 4096 edges/block, 391 blocks. Packed word: src(16)|dstlow(7)<<16|bucket(9)<<23.
__global__ __launch_bounds__(PT) void partition(
    const int* __restrict__ ei, int* __restrict__ gcur,
    unsigned int* __restrict__ barr)
{
    __shared__ int hist[NBUK];
    __shared__ int start[NBUK];
    __shared__ int gbase[NBUK];
    __shared__ int lofs[NBUK];
    __shared__ int wsum[8];
    __shared__ int woff[8];
    __shared__ unsigned int buf[CHUNK];

    int tid = threadIdx.x;
    int lane = tid & 63, wid = tid >> 6;
    int cbase = blockIdx.x * CHUNK;
    int cnt = N_EDGES - cbase;
    if (cnt > CHUNK) cnt = CHUNK;
    int n4 = cnt >> 2;                        // cnt always divisible by 4

    for (int i = tid; i < NBUK; i += PT) { hist[i] = 0; lofs[i] = 0; }
    __syncthreads();

    const int4* s4 = (const int4*)ei + (cbase >> 2);
    const int4* d4 = (const int4*)(ei + N_EDGES) + (cbase >> 2);

    // load edges ONCE into registers; histogram as we go
    int4 dv[2], sv[2];
#pragma unroll
    for (int i = 0; i < 2; ++i) {
        int k = i * PT + tid;
        if (k < n4) {
            dv[i] = d4[k]; sv[i] = s4[k];
            atomicAdd(&hist[dv[i].x >> 7], 1);
            atomicAdd(&hist[dv[i].y >> 7], 1);
            atomicAdd(&hist[dv[i].z >> 7], 1);
            atomicAdd(&hist[dv[i].w >> 7], 1);
        }
    }
    __syncthreads();

    // wave-shfl inclusive scan over NBUK (padded to 512)
    int a = (tid < NBUK) ? hist[tid] : 0;
    int orig = a;
#pragma unroll
    for (int off = 1; off < 64; off <<= 1) {
        int u = __shfl_up(a, off);
        if (lane >= off) a += u;
    }
    if (lane == 63) wsum[wid] = a;
    __syncthreads();
    if (tid == 0) {
        int r = 0;
#pragma unroll
        for (int w = 0; w < 8; ++w) { woff[w] = r; r += wsum[w]; }
    }
    __syncthreads();
    a += woff[wid];
    if (tid < NBUK) {
        start[tid] = a - orig;                              // exclusive
        gbase[tid] = atomicAdd(&gcur[tid], orig);           // reserve global span
    }
    __syncthreads();

    // reorder from registers into LDS by bucket
#pragma unroll
    for (int i = 0; i < 2; ++i) {
        int k = i * PT + tid;
        if (k < n4) {
            int dd[4] = {dv[i].x, dv[i].y, dv[i].z, dv[i].w};
            int ss[4] = {sv[i].x, sv[i].y, sv[i].z, sv[i].w};
#pragma unroll
            for (int e = 0; e < 4; ++e) {
                int d = dd[e];
                int bkt = d >> 7;
                int loc = atomicAdd(&lofs[bkt], 1);
                buf[start[bkt] + loc] =
                    (unsigned)ss[e] | ((unsigned)(d & 127) << 16) | ((unsigned)bkt << 23);
            }
        }
    }
    __syncthreads();

    // coalesced flush
    for (int i = tid; i < cnt; i += PT) {
        unsigned u = buf[i];
        int bkt = u >> 23;
        int g = gbase[bkt] + (i - start[bkt]);
        if (g < BCAP) barr[(size_t)bkt * BCAP + g] = u & 0x7FFFFFu;
    }
}

// ---------------- merged order + aggregation, half-bucket blocks -------------
// 2 blocks per bucket, 512 threads (8 waves). Phase 1: scan the bucket's
// entries, demux THIS block's 64 nodes into LDS lists. Phase 2: 2 nodes/wave
// (half-wave each; lane c owns (head0,c)+(head1,c) via head-interleaved hI).
// Inner loop: 2 shfl + 1 dword gather + ONE v_pk_fma_f16 per edge (both heads).
__global__ __launch_bounds__(512) void aggregate(
    const unsigned int* __restrict__ hI, const float* __restrict__ as_,
    const float* __restrict__ ad_, const int* __restrict__ gcur,
    const unsigned int* __restrict__ barr, const float* __restrict__ bias,
    float* __restrict__ out)
{
    __shared__ unsigned short lcol[64 * CAP];   // 10.2 KB
    __shared__ int hist[64];

    int b    = blockIdx.x >> 1;
    int jbase = (blockIdx.x & 1) << 6;          // 0 or 64
    int tid  = threadIdx.x;
    if (tid < 64) hist[tid] = 0;
    __syncthreads();

    int cnt = gcur[b];
    if (cnt > BCAP) cnt = BCAP;
    const unsigned int* bb = barr + (size_t)b * BCAP;

    for (int i = tid; i < cnt; i += 512) {
        unsigned u = bb[i];
        int r = ((int)(u >> 16) & 127) - jbase;
        if ((unsigned)r < 64u) {
            int k = atomicAdd(&hist[r], 1);
            if (k < CAP) lcol[r * CAP + k] = (unsigned short)(u & 0xFFFFu);
        }
    }
    __syncthreads();

    int lane = tid & 63;
    int wave = tid >> 6;                 // 0..7
    int c    = lane & 31;
    int hv   = lane >> 5;                // which node of the wave's pair
    int sl   = lane & 32;                // shuffle source-half base
    float bi0 = bias[c], bi1 = bias[32 + c];

    for (int pass = 0; pass < 4; ++pass) {
        int r = pass * 16 + (wave << 1) + hv;
        int node = b * 128 + jbase + r;
        bool valid = (node < N_NODES);

        float2 adv = valid ? *(const float2*)(ad_ + node * 2) : make_float2(0.f, 0.f);
        float2 asv = valid ? *(const float2*)(as_ + node * 2) : make_float2(0.f, 0.f);

        // self-loop (kept in f32)
        float t0 = asv.x + adv.x, t1 = asv.y + adv.y;
        float e0 = (t0 > 0.f) ? t0 : NEG * t0;
        float e1 = (t1 > 0.f) ? t1 : NEG * t1;
        float p0s = __expf(e0), p1s = __expf(e1);
        unsigned hs = valid ? hI[(unsigned)node * 32u + c] : 0u;
        __half2 hsh = u2h2(hs);
        float self0 = p0s * __half2float(__low2half(hsh));
        float self1 = p1s * __half2float(__high2half(hsh));
        float s0 = 0.f, s1 = 0.f;

        __half2 z = __float2half2_rn(0.f);
        __half2 acA = z, acB = z, acC = z, acD = z;

        int n = valid ? min(hist[r], CAP) : 0;
        const unsigned short* cb = &lcol[r * CAP];
        int nmax = max(n, __shfl_xor(n, 32));

        for (int base = 0; base < nmax; base += 32) {
            unsigned msrc = 0, packP = 0;
            int myidx = base + c;
            if (myidx < n) {
                int srci = (int)cb[myidx];
                float2 av = *(const float2*)(as_ + srci * 2);
                float u0 = av.x + adv.x, u1 = av.y + adv.y;
                float f0 = (u0 > 0.f) ? u0 : NEG * u0;
                float f1 = (u1 > 0.f) ? u1 : NEG * u1;
                float q0 = __expf(f0), q1 = __expf(f1);
                s0 += q0; s1 += q1;
                msrc  = (unsigned)srci;
                packP = (unsigned)__half_as_ushort(__float2half_rn(q0)) |
                        ((unsigned)__half_as_ushort(__float2half_rn(q1)) << 16);
            }
            int c32 = nmax - base;
            if (c32 > 32) c32 = 32;

            int jj = 0;
            for (; jj + 8 <= c32; jj += 8) {
                unsigned sA = __shfl(msrc, sl + jj);
                unsigned sB = __shfl(msrc, sl + jj + 1);
                unsigned sC = __shfl(msrc, sl + jj + 2);
                unsigned sD = __shfl(msrc, sl + jj + 3);
                unsigned sE = __shfl(msrc, sl + jj + 4);
                unsigned sF = __shfl(msrc, sl + jj + 5);
                unsigned sG = __shfl(msrc, sl + jj + 6);
                unsigned sH = __shfl(msrc, sl + jj + 7);
                unsigned pA = __shfl(packP, sl + jj);
                unsigned pB = __shfl(packP, sl + jj + 1);
                unsigned pC = __shfl(packP, sl + jj + 2);
                unsigned pD = __shfl(packP, sl + jj + 3);
                unsigned pE = __shfl(packP, sl + jj + 4);
                unsigned pF = __shfl(packP, sl + jj + 5);
                unsigned pG = __shfl(packP, sl + jj + 6);
                unsigned pH = __shfl(packP, sl + jj + 7);
                unsigned vA = hI[sA * 32u + c];
                unsigned vB = hI[sB * 32u + c];
                unsigned vC = hI[sC * 32u + c];
                unsigned vD = hI[sD * 32u + c];
                unsigned vE = hI[sE * 32u + c];
                unsigned vF = hI[sF * 32u + c];
                unsigned vG = hI[sG * 32u + c];
                unsigned vH = hI[sH * 32u + c];
                acA = __hfma2(u2h2(vA), u2h2(pA), acA);
                acB = __hfma2(u2h2(vB), u2h2(pB), acB);
                acC = __hfma2(u2h2(vC), u2h2(pC), acC);
                acD = __hfma2(u2h2(vD), u2h2(pD), acD);
                acA = __hfma2(u2h2(vE), u2h2(pE), acA);
                acB = __hfma2(u2h2(vF), u2h2(pF), acB);
                acC = __hfma2(u2h2(vG), u2h2(pG), acC);
                acD = __hfma2(u2h2(vH), u2h2(pH), acD);
            }
            for (; jj < c32; ++jj) {
                unsigned sA = __shfl(msrc, sl + jj);
                unsigned pA = __shfl(packP, sl + jj);
                unsigned vA = hI[sA * 32u + c];
                acA = __hfma2(u2h2(vA), u2h2(pA), acA);
            }
        }

        // combine chains in f32
        float2 fA = __half22float2(acA);
        float2 fB = __half22float2(acB);
        float2 fC = __half22float2(acC);
        float2 fD = __half22float2(acD);
        float acc0 = (fA.x + fB.x) + (fC.x + fD.x) + self0;
        float acc1 = (fA.y + fB.y) + (fC.y + fD.y) + self1;

        // reduce denominators within the half-wave (xor <= 16 stays inside)
        s0 += __shfl_xor(s0, 16); s1 += __shfl_xor(s1, 16);
        s0 += __shfl_xor(s0, 8);  s1 += __shfl_xor(s1, 8);
        s0 += __shfl_xor(s0, 4);  s1 += __shfl_xor(s1, 4);
        s0 += __shfl_xor(s0, 2);  s1 += __shfl_xor(s1, 2);
        s0 += __shfl_xor(s0, 1);  s1 += __shfl_xor(s1, 1);
        s0 += p0s; s1 += p1s;

        if (valid) {
            out[(size_t)node * 64 + c]      = acc0 / s0 + bi0;
            out[(size_t)node * 64 + 32 + c] = acc1 / s1 + bi1;
        }
    }
}

extern "C" void kernel_launch(void* const* d_in, const int* in_sizes, int n_in,
                              void* d_out, int out_size, void* d_ws, size_t ws_size,
                              hipStream_t stream)
{
    const float* x       = (const float*)d_in[0];
    const int*   ei      = (const int*)d_in[1];
    const float* W       = (const float*)d_in[2];
    const float* att_src = (const float*)d_in[3];
    const float* att_dst = (const float*)d_in[4];
    const float* bias    = (const float*)d_in[5];
    float* out = (float*)d_out;

    char* ws = (char*)d_ws;
    size_t off = 0;
    auto alloc = [&](size_t bytes) -> void* {
        void* p = ws + off;
        off = (off + bytes + 511) & ~(size_t)511;
        return p;
    };
    unsigned int* hI  = (unsigned int*)alloc((size_t)N_NODES * 32 * 4);
    float*  as_ = (float*)alloc((size_t)N_NODES * 2 * 4);
    float*  ad_ = (float*)alloc((size_t)N_NODES * 2 * 4);
    int*    gcur = (int*)alloc((size_t)NBUK * 4);
    unsigned int* barr = (unsigned int*)alloc((size_t)NBUK * BCAP * 4);

    gemm_logits<<<(N_NODES * 4 + 255) / 256, 256, 0, stream>>>(
        x, W, att_src, att_dst, hI, as_, ad_, gcur);
    partition<<<P_BLOCKS, PT, 0, stream>>>(ei, gcur, barr);
    aggregate<<<NBUK * 2, 512, 0, stream>>>(hI, as_, ad_, gcur, barr, bias, out);
}

// Round 14
// 81.449 us; speedup vs baseline: 1.1242x; 1.0208x over previous
//
#include <hip/hip_runtime.h>
#include <hip/hip_fp16.h>

#define N_NODES 50000
#define N_EDGES 1600000
#define IN_CH   128
#define NEG     0.2f
#define NBUK    391      // buckets of 128 node-ids: bucket = dst >> 7
#define BCAP    4608     // per-bucket edge capacity (mean 4096, +8 sigma)
#define CAP     80       // per-node list capacity (mean deg 32, +8.5 sigma)
#define CHUNK   4096
#define P_BLOCKS 391     // ceil(E / CHUNK)
#define PT      512      // partition threads

static __device__ __forceinline__ __half2 u2h2(unsigned u) {
    union { unsigned u; __half2 h; } x; x.u = u; return x.h;
}

// ---------------- GEMM h = x @ W (+ fused attention logits) ------------------
// 4 threads/row (16 cols each). Output hI is HEAD-INTERLEAVED:
// hI[row*32 + c] = u32( f16 h[row][c] , f16 h[row][32+c] )  (lo=head0, hi=head1)
// Block 0 also zeroes gcur (replaces a fillBuffer dispatch).
__global__ __launch_bounds__(256) void gemm_logits(
    const float* __restrict__ x, const float* __restrict__ W,
    const float* __restrict__ att_src, const float* __restrict__ att_dst,
    unsigned int* __restrict__ hI, float* __restrict__ as_, float* __restrict__ ad_,
    int* __restrict__ gcur)
{
    if (blockIdx.x == 0) {
        for (int i = threadIdx.x; i < NBUK; i += 256) gcur[i] = 0;
    }

    __shared__ float Wl[IN_CH * 64];
    for (int i = threadIdx.x; i < IN_CH * 64; i += 256) Wl[i] = W[i];
    __syncthreads();

    int gid = blockIdx.x * 256 + threadIdx.x;
    int row = gid >> 2;
    int sub = gid & 3;            // 16-col slice; head = sub>>1
    if (row >= N_NODES) return;

    float acc[16];
#pragma unroll
    for (int c = 0; c < 16; ++c) acc[c] = 0.f;

    const float* xr = x + (size_t)row * IN_CH;
    for (int k = 0; k < IN_CH; k += 4) {
        float4 xv = *(const float4*)(xr + k);
        float xs[4] = {xv.x, xv.y, xv.z, xv.w};
#pragma unroll
        for (int kk = 0; kk < 4; ++kk) {
            const float* wr = &Wl[(k + kk) * 64 + sub * 16];
#pragma unroll
            for (int c = 0; c < 16; c += 4) {
                float4 wv = *(const float4*)(wr + c);
                acc[c]     += xs[kk] * wv.x;
                acc[c + 1] += xs[kk] * wv.y;
                acc[c + 2] += xs[kk] * wv.z;
                acc[c + 3] += xs[kk] * wv.w;
            }
        }
    }

    // exchange with partner (sub^2): head0 thread gets head1 values
    float part[16];
#pragma unroll
    for (int i = 0; i < 16; ++i) part[i] = __shfl_xor(acc[i], 2);

    if (sub < 2) {   // head0 owner: pack (h0, h1) pairs for cols sub*16+i
        union { unsigned int u[16]; uint4 v4[4]; } pk;
#pragma unroll
        for (int i = 0; i < 16; ++i) {
            pk.u[i] = (unsigned)__half_as_ushort(__float2half_rn(acc[i])) |
                      ((unsigned)__half_as_ushort(__float2half_rn(part[i])) << 16);
        }
        uint4* hp = (uint4*)(hI + (size_t)row * 32 + sub * 16);
#pragma unroll
        for (int i = 0; i < 4; ++i) hp[i] = pk.v4[i];
    }

    float s = 0.f, d = 0.f;
#pragma unroll
    for (int c = 0; c < 16; ++c) {
        s += acc[c] * att_src[sub * 16 + c];
        d += acc[c] * att_dst[sub * 16 + c];
    }
    s += __shfl_xor(s, 1);
    d += __shfl_xor(d, 1);
    if ((sub & 1) == 0) {
        as_[row * 2 + (sub >> 1)] = s;
        ad_[row * 2 + (sub >> 1)] = d;
    }
}

// ---------------- LDS-staged radix partition (register-cached edges) ---------
// 4096 edges/block, 391 blocks. Packed word: src(16)|dstlow(7)<<16|bucket(9)<<23.
__global__ __launch_bounds__(PT) void partition(
    const int* __restrict__ ei, int* __restrict__ gcur,
    unsigned int* __restrict__ barr)
{
    __shared__ int hist[NBUK];
    __shared__ int start[NBUK];
    __shared__ int gbase[NBUK];
    __shared__ int lofs[NBUK];
    __shared__ int wsum[8];
    __shared__ int woff[8];
    __shared__ unsigned int buf[CHUNK];

    int tid = threadIdx.x;
    int lane = tid & 63, wid = tid >> 6;
    int cbase = blockIdx.x * CHUNK;
    int cnt = N_EDGES - cbase;
    if (cnt > CHUNK) cnt = CHUNK;
    int n4 = cnt >> 2;                        // cnt always divisible by 4

    for (int i = tid; i < NBUK; i += PT) { hist[i] = 0; lofs[i] = 0; }
    __syncthreads();

    const int4* s4 = (const int4*)ei + (cbase >> 2);
    const int4* d4 = (const int4*)(ei + N_EDGES) + (cbase >> 2);

    // load edges ONCE into registers; histogram as we go
    int4 dv[2], sv[2];
#pragma unroll
    for (int i = 0; i < 2; ++i) {
        int k = i * PT + tid;
        if (k < n4) {
            dv[i] = d4[k]; sv[i] = s4[k];
            atomicAdd(&hist[dv[i].x >> 7], 1);
            atomicAdd(&hist[dv[i].y >> 7], 1);
            atomicAdd(&hist[dv[i].z >> 7], 1);
            atomicAdd(&hist[dv[i].w >> 7], 1);
        }
    }
    __syncthreads();

    // wave-shfl inclusive scan over NBUK (padded to 512)
    int a = (tid < NBUK) ? hist[tid] : 0;
    int orig = a;
#pragma unroll
    for (int off = 1; off < 64; off <<= 1) {
        int u = __shfl_up(a, off);
        if (lane >= off) a += u;
    }
    if (lane == 63) wsum[wid] = a;
    __syncthreads();
    if (tid == 0) {
        int r = 0;
#pragma unroll
        for (int w = 0; w < 8; ++w) { woff[w] = r; r += wsum[w]; }
    }
    __syncthreads();
    a += woff[wid];
    if (tid < NBUK) {
        start[tid] = a - orig;                              // exclusive
        gbase[tid] = atomicAdd(&gcur[tid], orig);           // reserve global span
    }
    __syncthreads();

    // reorder from registers into LDS by bucket
#pragma unroll
    for (int i = 0; i < 2; ++i) {
        int k = i * PT + tid;
        if (k < n4) {
            int dd[4] = {dv[i].x, dv[i].y, dv[i].z, dv[i].w};
            int ss[4] = {sv[i].x, sv[i].y, sv[i].z, sv[i].w};
#pragma unroll
            for (int e = 0; e < 4; ++e) {
                int d = dd[e];
                int bkt = d >> 7;
                int loc = atomicAdd(&lofs[bkt], 1);
                buf[start[bkt] + loc] =
                    (unsigned)ss[e] | ((unsigned)(d & 127) << 16) | ((unsigned)bkt << 23);
            }
        }
    }
    __syncthreads();

    // coalesced flush
    for (int i = tid; i < cnt; i += PT) {
        unsigned u = buf[i];
        int bkt = u >> 23;
        int g = gbase[bkt] + (i - start[bkt]);
        if (g < BCAP) barr[(size_t)bkt * BCAP + g] = u & 0x7FFFFFu;
    }
}

// ---------------- merged order + aggregation, quarter-bucket blocks ----------
// 4 blocks per bucket, 512 threads (8 waves), 32 nodes per block -> grid 1564
// (6.1 blocks/CU, 4 resident = 32 waves/CU). Phase 1: scan the bucket's
// entries, demux THIS block's 32 nodes into LDS lists (5.2 KB). Phase 2:
// 2 nodes/wave (half-wave each; lane c owns (head0,c)+(head1,c) via
// head-interleaved hI); inner loop 2 shfl + 1 dword gather + 1 v_pk_fma_f16
// per edge, 8 gathers in flight.
__global__ __launch_bounds__(512) void aggregate(
    const unsigned int* __restrict__ hI, const float* __restrict__ as_,
    const float* __restrict__ ad_, const int* __restrict__ gcur,
    const unsigned int* __restrict__ barr, const float* __restrict__ bias,
    float* __restrict__ out)
{
    __shared__ unsigned short lcol[32 * CAP];   // 5.1 KB
    __shared__ int hist[32];

    int b     = blockIdx.x >> 2;
    int jbase = (blockIdx.x & 3) << 5;          // 0,32,64,96
    int tid   = threadIdx.x;
    if (tid < 32) hist[tid] = 0;
    __syncthreads();

    int cnt = gcur[b];
    if (cnt > BCAP) cnt = BCAP;
    const unsigned int* bb = barr + (size_t)b * BCAP;

    for (int i = tid; i < cnt; i += 512) {
        unsigned u = bb[i];
        int r = ((int)(u >> 16) & 127) - jbase;
        if ((unsigned)r < 32u) {
            int k = atomicAdd(&hist[r], 1);
            if (k < CAP) lcol[r * CAP + k] = (unsigned short)(u & 0xFFFFu);
        }
    }
    __syncthreads();

    int lane = tid & 63;
    int wave = tid >> 6;                 // 0..7
    int c    = lane & 31;
    int hv   = lane >> 5;                // which node of the wave's pair
    int sl   = lane & 32;                // shuffle source-half base
    float bi0 = bias[c], bi1 = bias[32 + c];

    for (int pass = 0; pass < 2; ++pass) {
        int r = pass * 16 + (wave << 1) + hv;
        int node = b * 128 + jbase + r;
        bool valid = (node < N_NODES);

        float2 adv = valid ? *(const float2*)(ad_ + node * 2) : make_float2(0.f, 0.f);
        float2 asv = valid ? *(const float2*)(as_ + node * 2) : make_float2(0.f, 0.f);

        // self-loop (kept in f32)
        float t0 = asv.x + adv.x, t1 = asv.y + adv.y;
        float e0 = (t0 > 0.f) ? t0 : NEG * t0;
        float e1 = (t1 > 0.f) ? t1 : NEG * t1;
        float p0s = __expf(e0), p1s = __expf(e1);
        unsigned hs = valid ? hI[(unsigned)node * 32u + c] : 0u;
        __half2 hsh = u2h2(hs);
        float self0 = p0s * __half2float(__low2half(hsh));
        float self1 = p1s * __half2float(__high2half(hsh));
        float s0 = 0.f, s1 = 0.f;

        __half2 z = __float2half2_rn(0.f);
        __half2 acA = z, acB = z, acC = z, acD = z;

        int n = valid ? min(hist[r], CAP) : 0;
        const unsigned short* cb = &lcol[r * CAP];
        int nmax = max(n, __shfl_xor(n, 32));

        for (int base = 0; base < nmax; base += 32) {
            unsigned msrc = 0, packP = 0;
            int myidx = base + c;
            if (myidx < n) {
                int srci = (int)cb[myidx];
                float2 av = *(const float2*)(as_ + srci * 2);
                float u0 = av.x + adv.x, u1 = av.y + adv.y;
                float f0 = (u0 > 0.f) ? u0 : NEG * u0;
                float f1 = (u1 > 0.f) ? u1 : NEG * u1;
                float q0 = __expf(f0), q1 = __expf(f1);
                s0 += q0; s1 += q1;
                msrc  = (unsigned)srci;
                packP = (unsigned)__half_as_ushort(__float2half_rn(q0)) |
                        ((unsigned)__half_as_ushort(__float2half_rn(q1)) << 16);
            }
            int c32 = nmax - base;
            if (c32 > 32) c32 = 32;

            int jj = 0;
            for (; jj + 8 <= c32; jj += 8) {
                unsigned sA = __shfl(msrc, sl + jj);
                unsigned sB = __shfl(msrc, sl + jj + 1);
                unsigned sC = __shfl(msrc, sl + jj + 2);
                unsigned sD = __shfl(msrc, sl + jj + 3);
                unsigned sE = __shfl(msrc, sl + jj + 4);
                unsigned sF = __shfl(msrc, sl + jj + 5);
                unsigned sG = __shfl(msrc, sl + jj + 6);
                unsigned sH = __shfl(msrc, sl + jj + 7);
                unsigned pA = __shfl(packP, sl + jj);
                unsigned pB = __shfl(packP, sl + jj + 1);
                unsigned pC = __shfl(packP, sl + jj + 2);
                unsigned pD = __shfl(packP, sl + jj + 3);
                unsigned pE = __shfl(packP, sl + jj + 4);
                unsigned pF = __shfl(packP, sl + jj + 5);
                unsigned pG = __shfl(packP, sl + jj + 6);
                unsigned pH = __shfl(packP, sl + jj + 7);
                unsigned vA = hI[sA * 32u + c];
                unsigned vB = hI[sB * 32u + c];
                unsigned vC = hI[sC * 32u + c];
                unsigned vD = hI[sD * 32u + c];
                unsigned vE = hI[sE * 32u + c];
                unsigned vF = hI[sF * 32u + c];
                unsigned vG = hI[sG * 32u + c];
                unsigned vH = hI[sH * 32u + c];
                acA = __hfma2(u2h2(vA), u2h2(pA), acA);
                acB = __hfma2(u2h2(vB), u2h2(pB), acB);
                acC = __hfma2(u2h2(vC), u2h2(pC), acC);
                acD = __hfma2(u2h2(vD), u2h2(pD), acD);
                acA = __hfma2(u2h2(vE), u2h2(pE), acA);
                acB = __hfma2(u2h2(vF), u2h2(pF), acB);
                acC = __hfma2(u2h2(vG), u2h2(pG), acC);
                acD = __hfma2(u2h2(vH), u2h2(pH), acD);
            }
            for (; jj < c32; ++jj) {
                unsigned sA = __shfl(msrc, sl + jj);
                unsigned pA = __shfl(packP, sl + jj);
                unsigned vA = hI[sA * 32u + c];
                acA = __hfma2(u2h2(vA), u2h2(pA), acA);
            }
        }

        // combine chains in f32
        float2 fA = __half22float2(acA);
        float2 fB = __half22float2(acB);
        float2 fC = __half22float2(acC);
        float2 fD = __half22float2(acD);
        float acc0 = (fA.x + fB.x) + (fC.x + fD.x) + self0;
        float acc1 = (fA.y + fB.y) + (fC.y + fD.y) + self1;

        // reduce denominators within the half-wave (xor <= 16 stays inside)
        s0 += __shfl_xor(s0, 16); s1 += __shfl_xor(s1, 16);
        s0 += __shfl_xor(s0, 8);  s1 += __shfl_xor(s1, 8);
        s0 += __shfl_xor(s0, 4);  s1 += __shfl_xor(s1, 4);
        s0 += __shfl_xor(s0, 2);  s1 += __shfl_xor(s1, 2);
        s0 += __shfl_xor(s0, 1);  s1 += __shfl_xor(s1, 1);
        s0 += p0s; s1 += p1s;

        if (valid) {
            out[(size_t)node * 64 + c]      = acc0 / s0 + bi0;
            out[(size_t)node * 64 + 32 + c] = acc1 / s1 + bi1;
        }
    }
}

extern "C" void kernel_launch(void* const* d_in, const int* in_sizes, int n_in,
                              void* d_out, int out_size, void* d_ws, size_t ws_size,
                              hipStream_t stream)
{
    const float* x       = (const float*)d_in[0];
    const int*   ei      = (const int*)d_in[1];
    const float* W       = (const float*)d_in[2];
    const float* att_src = (const float*)d_in[3];
    const float* att_dst = (const float*)d_in[4];
    const float* bias    = (const float*)d_in[5];
    float* out = (float*)d_out;

    char* ws = (char*)d_ws;
    size_t off = 0;
    auto alloc = [&](size_t bytes) -> void* {
        void* p = ws + off;
        off = (off + bytes + 511) & ~(size_t)511;
        return p;
    };
    unsigned int* hI  = (unsigned int*)alloc((size_t)N_NODES * 32 * 4);
    float*  as_ = (float*)alloc((size_t)N_NODES * 2 * 4);
    float*  ad_ = (float*)alloc((size_t)N_NODES * 2 * 4);
    int*    gcur = (int*)alloc((size_t)NBUK * 4);
    unsigned int* barr = (unsigned int*)alloc((size_t)NBUK * BCAP * 4);

    gemm_logits<<<(N_NODES * 4 + 255) / 256, 256, 0, stream>>>(
        x, W, att_src, att_dst, hI, as_, ad_, gcur);
    partition<<<P_BLOCKS, PT, 0, stream>>>(ei, gcur, barr);
    aggregate<<<NBUK * 4, 512, 0, stream>>>(hI, as_, ad_, gcur, barr, bias, out);
}

// Round 15
// 80.879 us; speedup vs baseline: 1.1321x; 1.0070x over previous
//
#include <hip/hip_runtime.h>
#include <hip/hip_fp16.h>

#define N_NODES 50000
#define N_EDGES 1600000
#define IN_CH   128
#define NEG     0.2f
#define NBUK    391      // buckets of 128 node-ids: bucket = dst >> 7
#define BCAP    4608     // per-bucket edge capacity (mean 4096, +8 sigma)
#define CAP     80       // per-node list capacity (mean deg 32, +8.5 sigma)
#define CHUNK   4096
#define P_BLOCKS 391     // ceil(E / CHUNK)
#define G_BLOCKS 391     // 512 thr, 4 thr/row -> 128 rows/block

static __device__ __forceinline__ __half2 u2h2(unsigned u) {
    union { unsigned u; __half2 h; } x; x.u = u; return x.h;
}

// ---------------- tiny: zero gcur (must precede fused kernel) ----------------
__global__ void zero_gcur(int* __restrict__ gcur)
{
    if (threadIdx.x < NBUK) gcur[threadIdx.x] = 0;
}

// ---------------- fused: partition (blocks [0,391)) || gemm (blocks [391,782))
// Partition: LDS-staged radix partition of edges into 391 dst-buckets.
//   Packed word: src(16) | dstlow(7)<<16 | bucket(9)<<23.
// GEMM: h = x @ W + fused attention logits; 4 threads/row (16 cols each).
//   hI[row*32+c] = u32(f16 h[row][c], f16 h[row][32+c]) head-interleaved.
// Partition blocks first (longer), so they dispatch/start first.
__global__ __launch_bounds__(512, 6) void fused_gp(
    const int* __restrict__ ei, int* __restrict__ gcur,
    unsigned int* __restrict__ barr,
    const float* __restrict__ x, const float* __restrict__ W,
    const float* __restrict__ att_src, const float* __restrict__ att_dst,
    unsigned int* __restrict__ hI, float* __restrict__ as_, float* __restrict__ ad_)
{
    __shared__ union {
        struct {
            int hist[NBUK], start[NBUK], gbase[NBUK], lofs[NBUK];
            int wsum[8], woff[8];
            unsigned int buf[CHUNK];
        } p;
        float w[IN_CH * 64];
    } sm;

    int tid = threadIdx.x;

    if (blockIdx.x < P_BLOCKS) {
        // ---------------- partition branch ----------------
        int lane = tid & 63, wid = tid >> 6;
        int cbase = blockIdx.x * CHUNK;
        int cnt = N_EDGES - cbase;
        if (cnt > CHUNK) cnt = CHUNK;
        int n4 = cnt >> 2;

        for (int i = tid; i < NBUK; i += 512) { sm.p.hist[i] = 0; sm.p.lofs[i] = 0; }
        __syncthreads();

        const int4* s4 = (const int4*)ei + (cbase >> 2);
        const int4* d4 = (const int4*)(ei + N_EDGES) + (cbase >> 2);

        int4 dv[2], sv[2];
#pragma unroll
        for (int i = 0; i < 2; ++i) {
            int k = i * 512 + tid;
            if (k < n4) {
                dv[i] = d4[k]; sv[i] = s4[k];
                atomicAdd(&sm.p.hist[dv[i].x >> 7], 1);
                atomicAdd(&sm.p.hist[dv[i].y >> 7], 1);
                atomicAdd(&sm.p.hist[dv[i].z >> 7], 1);
                atomicAdd(&sm.p.hist[dv[i].w >> 7], 1);
            }
        }
        __syncthreads();

        int a = (tid < NBUK) ? sm.p.hist[tid] : 0;
        int orig = a;
#pragma unroll
        for (int off = 1; off < 64; off <<= 1) {
            int u = __shfl_up(a, off);
            if (lane >= off) a += u;
        }
        if (lane == 63) sm.p.wsum[wid] = a;
        __syncthreads();
        if (tid == 0) {
            int r = 0;
#pragma unroll
            for (int w = 0; w < 8; ++w) { sm.p.woff[w] = r; r += sm.p.wsum[w]; }
        }
        __syncthreads();
        a += sm.p.woff[wid];
        if (tid < NBUK) {
            sm.p.start[tid] = a - orig;
            sm.p.gbase[tid] = atomicAdd(&gcur[tid], orig);
        }
        __syncthreads();

#pragma unroll
        for (int i = 0; i < 2; ++i) {
            int k = i * 512 + tid;
            if (k < n4) {
                int dd[4] = {dv[i].x, dv[i].y, dv[i].z, dv[i].w};
                int ss[4] = {sv[i].x, sv[i].y, sv[i].z, sv[i].w};
#pragma unroll
                for (int e = 0; e < 4; ++e) {
                    int d = dd[e];
                    int bkt = d >> 7;
                    int loc = atomicAdd(&sm.p.lofs[bkt], 1);
                    sm.p.buf[sm.p.start[bkt] + loc] =
                        (unsigned)ss[e] | ((unsigned)(d & 127) << 16) | ((unsigned)bkt << 23);
                }
            }
        }
        __syncthreads();

        for (int i = tid; i < cnt; i += 512) {
            unsigned u = sm.p.buf[i];
            int bkt = u >> 23;
            int g = sm.p.gbase[bkt] + (i - sm.p.start[bkt]);
            if (g < BCAP) barr[(size_t)bkt * BCAP + g] = u & 0x7FFFFFu;
        }
    } else {
        // ---------------- gemm branch ----------------
        for (int i = tid; i < IN_CH * 64; i += 512) sm.w[i] = W[i];
        __syncthreads();

        int gid = (blockIdx.x - P_BLOCKS) * 512 + tid;
        int row = gid >> 2;
        int sub = gid & 3;            // 16-col slice; head = sub>>1
        if (row >= N_NODES) return;

        float acc[16];
#pragma unroll
        for (int c = 0; c < 16; ++c) acc[c] = 0.f;

        const float* xr = x + (size_t)row * IN_CH;
        for (int k = 0; k < IN_CH; k += 4) {
            float4 xv = *(const float4*)(xr + k);
            float xs[4] = {xv.x, xv.y, xv.z, xv.w};
#pragma unroll
            for (int kk = 0; kk < 4; ++kk) {
                const float* wr = &sm.w[(k + kk) * 64 + sub * 16];
#pragma unroll
                for (int c = 0; c < 16; c += 4) {
                    float4 wv = *(const float4*)(wr + c);
                    acc[c]     += xs[kk] * wv.x;
                    acc[c + 1] += xs[kk] * wv.y;
                    acc[c + 2] += xs[kk] * wv.z;
                    acc[c + 3] += xs[kk] * wv.w;
                }
            }
        }

        // exchange with partner (sub^2): head0 thread gets head1 values
        float part[16];
#pragma unroll
        for (int i = 0; i < 16; ++i) part[i] = __shfl_xor(acc[i], 2);

        if (sub < 2) {   // head0 owner: pack (h0, h1) pairs for cols sub*16+i
            union { unsigned int u[16]; uint4 v4[4]; } pk;
#pragma unroll
            for (int i = 0; i < 16; ++i) {
                pk.u[i] = (unsigned)__half_as_ushort(__float2half_rn(acc[i])) |
                          ((unsigned)__half_as_ushort(__float2half_rn(part[i])) << 16);
            }
            uint4* hp = (uint4*)(hI + (size_t)row * 32 + sub * 16);
#pragma unroll
            for (int i = 0; i < 4; ++i) hp[i] = pk.v4[i];
        }

        float s = 0.f, d = 0.f;
#pragma unroll
        for (int c = 0; c < 16; ++c) {
            s += acc[c] * att_src[sub * 16 + c];
            d += acc[c] * att_dst[sub * 16 + c];
        }
        s += __shfl_xor(s, 1);
        d += __shfl_xor(d, 1);
        if ((sub & 1) == 0) {
            as_[row * 2 + (sub >> 1)] = s;
            ad_[row * 2 + (sub >> 1)] = d;
        }
    }
}

// ---------------- merged order + aggregation, quarter-bucket blocks ----------
// 4 blocks per bucket, 512 threads (8 waves), 32 nodes per block. Phase 1:
// scan the bucket's entries, demux THIS block's 32 nodes into LDS lists.
// Phase 2: 2 nodes/wave (half-wave each; lane c owns (head0,c)+(head1,c) via
// head-interleaved hI). Preload covers 64 edges per serial chain (2 packs per
// lane, both as_ gathers in flight together); inner loop 2 shfl + 1 dword
// gather + 1 v_pk_fma_f16 per edge, 8 gathers in flight.
__global__ __launch_bounds__(512) void aggregate(
    const unsigned int* __restrict__ hI, const float* __restrict__ as_,
    const float* __restrict__ ad_, const int* __restrict__ gcur,
    const unsigned int* __restrict__ barr, const float* __restrict__ bias,
    float* __restrict__ out)
{
    __shared__ unsigned short lcol[32 * CAP];   // 5.1 KB
    __shared__ int hist[32];

    int b     = blockIdx.x >> 2;
    int jbase = (blockIdx.x & 3) << 5;          // 0,32,64,96
    int tid   = threadIdx.x;
    if (tid < 32) hist[tid] = 0;
    __syncthreads();

    int cnt = gcur[b];
    if (cnt > BCAP) cnt = BCAP;
    const unsigned int* bb = barr + (size_t)b * BCAP;

    for (int i = tid; i < cnt; i += 512) {
        unsigned u = bb[i];
        int r = ((int)(u >> 16) & 127) - jbase;
        if ((unsigned)r < 32u) {
            int k = atomicAdd(&hist[r], 1);
            if (k < CAP) lcol[r * CAP + k] = (unsigned short)(u & 0xFFFFu);
        }
    }
    __syncthreads();

    int lane = tid & 63;
    int wave = tid >> 6;                 // 0..7
    int c    = lane & 31;
    int hv   = lane >> 5;                // which node of the wave's pair
    int sl   = lane & 32;                // shuffle source-half base
    float bi0 = bias[c], bi1 = bias[32 + c];

    for (int pass = 0; pass < 2; ++pass) {
        int r = pass * 16 + (wave << 1) + hv;
        int node = b * 128 + jbase + r;
        bool valid = (node < N_NODES);

        float2 adv = valid ? *(const float2*)(ad_ + node * 2) : make_float2(0.f, 0.f);
        float2 asv = valid ? *(const float2*)(as_ + node * 2) : make_float2(0.f, 0.f);

        // self-loop (kept in f32)
        float t0 = asv.x + adv.x, t1 = asv.y + adv.y;
        float e0 = (t0 > 0.f) ? t0 : NEG * t0;
        float e1 = (t1 > 0.f) ? t1 : NEG * t1;
        float p0s = __expf(e0), p1s = __expf(e1);
        unsigned hs = valid ? hI[(unsigned)node * 32u + c] : 0u;
        __half2 hsh = u2h2(hs);
        float self0 = p0s * __half2float(__low2half(hsh));
        float self1 = p1s * __half2float(__high2half(hsh));
        float s0 = 0.f, s1 = 0.f;

        __half2 z = __float2half2_rn(0.f);
        __half2 acA = z, acB = z, acC = z, acD = z;

        int n = valid ? min(hist[r], CAP) : 0;
        const unsigned short* cb = &lcol[r * CAP];
        int nmax = max(n, __shfl_xor(n, 32));

        for (int base = 0; base < nmax; base += 64) {
            // preload TWO 32-edge chunks: both as_ gathers issue together,
            // one exp/pack phase covers 64 edges.
            unsigned ms0 = 0, pp0 = 0, ms1 = 0, pp1 = 0;
            int i0 = base + c, i1 = base + 32 + c;
            int sA_ = (i0 < n) ? (int)cb[i0] : -1;
            int sB_ = (i1 < n) ? (int)cb[i1] : -1;
            float2 avA = (sA_ >= 0) ? *(const float2*)(as_ + sA_ * 2) : make_float2(0.f, 0.f);
            float2 avB = (sB_ >= 0) ? *(const float2*)(as_ + sB_ * 2) : make_float2(0.f, 0.f);
            if (sA_ >= 0) {
                float u0 = avA.x + adv.x, u1 = avA.y + adv.y;
                float f0 = (u0 > 0.f) ? u0 : NEG * u0;
                float f1 = (u1 > 0.f) ? u1 : NEG * u1;
                float q0 = __expf(f0), q1 = __expf(f1);
                s0 += q0; s1 += q1;
                ms0 = (unsigned)sA_;
                pp0 = (unsigned)__half_as_ushort(__float2half_rn(q0)) |
                      ((unsigned)__half_as_ushort(__float2half_rn(q1)) << 16);
            }
            if (sB_ >= 0) {
                float u0 = avB.x + adv.x, u1 = avB.y + adv.y;
                float f0 = (u0 > 0.f) ? u0 : NEG * u0;
                float f1 = (u1 > 0.f) ? u1 : NEG * u1;
                float q0 = __expf(f0), q1 = __expf(f1);
                s0 += q0; s1 += q1;
                ms1 = (unsigned)sB_;
                pp1 = (unsigned)__half_as_ushort(__float2half_rn(q0)) |
                      ((unsigned)__half_as_ushort(__float2half_rn(q1)) << 16);
            }

            int rem = nmax - base;
            int cA = rem < 32 ? rem : 32;
            int cB = rem - 32; if (cB < 0) cB = 0; else if (cB > 32) cB = 32;

            int jj = 0;
            for (; jj + 8 <= cA; jj += 8) {
                unsigned sA = __shfl(ms0, sl + jj);
                unsigned sB = __shfl(ms0, sl + jj + 1);
                unsigned sC = __shfl(ms0, sl + jj + 2);
                unsigned sD = __shfl(ms0, sl + jj + 3);
                unsigned sE = __shfl(ms0, sl + jj + 4);
                unsigned sF = __shfl(ms0, sl + jj + 5);
                unsigned sG = __shfl(ms0, sl + jj + 6);
                unsigned sH = __shfl(ms0, sl + jj + 7);
                unsigned pA = __shfl(pp0, sl + jj);
                unsigned pB = __shfl(pp0, sl + jj + 1);
                unsigned pC = __shfl(pp0, sl + jj + 2);
                unsigned pD = __shfl(pp0, sl + jj + 3);
                unsigned pE = __shfl(pp0, sl + jj + 4);
                unsigned pF = __shfl(pp0, sl + jj + 5);
                unsigned pG = __shfl(pp0, sl + jj + 6);
                unsigned pH = __shfl(pp0, sl + jj + 7);
                unsigned vA = hI[sA * 32u + c];
                unsigned vB = hI[sB * 32u + c];
                unsigned vC = hI[sC * 32u + c];
                unsigned vD = hI[sD * 32u + c];
                unsigned vE = hI[sE * 32u + c];
                unsigned vF = hI[sF * 32u + c];
                unsigned vG = hI[sG * 32u + c];
                unsigned vH = hI[sH * 32u + c];
                acA = __hfma2(u2h2(vA), u2h2(pA), acA);
                acB = __hfma2(u2h2(vB), u2h2(pB), acB);
                acC = __hfma2(u2h2(vC), u2h2(pC), acC);
                acD = __hfma2(u2h2(vD), u2h2(pD), acD);
                acA = __hfma2(u2h2(vE), u2h2(pE), acA);
                acB = __hfma2(u2h2(vF), u2h2(pF), acB);
                acC = __hfma2(u2h2(vG), u2h2(pG), acC);
                acD = __hfma2(u2h2(vH), u2h2(pH), acD);
            }
            for (; jj < cA; ++jj) {
                unsigned sA = __shfl(ms0, sl + jj);
                unsigned pA = __shfl(pp0, sl + jj);
                unsigned vA = hI[sA * 32u + c];
                acA = __hfma2(u2h2(vA), u2h2(pA), acA);
            }
            jj = 0;
            for (; jj + 8 <= cB; jj += 8) {
                unsigned sA = __shfl(ms1, sl + jj);
                unsigned sB = __shfl(ms1, sl + jj + 1);
                unsigned sC = __shfl(ms1, sl + jj + 2);
                unsigned sD = __shfl(ms1, sl + jj + 3);
                unsigned sE = __shfl(ms1, sl + jj + 4);
                unsigned sF = __shfl(ms1, sl + jj + 5);
                unsigned sG = __shfl(ms1, sl + jj + 6);
                unsigned sH = __shfl(ms1, sl + jj + 7);
                unsigned pA = __shfl(pp1, sl + jj);
                unsigned pB = __shfl(pp1, sl + jj + 1);
                unsigned pC = __shfl(pp1, sl + jj + 2);
                unsigned pD = __shfl(pp1, sl + jj + 3);
                unsigned pE = __shfl(pp1, sl + jj + 4);
                unsigned pF = __shfl(pp1, sl + jj + 5);
                unsigned pG = __shfl(pp1, sl + jj + 6);
                unsigned pH = __shfl(pp1, sl + jj + 7);
                unsigned vA = hI[sA * 32u + c];
                unsigned vB = hI[sB * 32u + c];
                unsigned vC = hI[sC * 32u + c];
                unsigned vD = hI[sD * 32u + c];
                unsigned vE = hI[sE * 32u + c];
                unsigned vF = hI[sF * 32u + c];
                unsigned vG = hI[sG * 32u + c];
                unsigned vH = hI[sH * 32u + c];
                acA = __hfma2(u2h2(vA), u2h2(pA), acA);
                acB = __hfma2(u2h2(vB), u2h2(pB), acB);
                acC = __hfma2(u2h2(vC), u2h2(pC), acC);
                acD = __hfma2(u2h2(vD), u2h2(pD), acD);
                acA = __hfma2(u2h2(vE), u2h2(pE), acA);
                acB = __hfma2(u2h2(vF), u2h2(pF), acB);
                acC = __hfma2(u2h2(vG), u2h2(pG), acC);
                acD = __hfma2(u2h2(vH), u2h2(pH), acD);
            }
            for (; jj < cB; ++jj) {
                unsigned sA = __shfl(ms1, sl + jj);
                unsigned pA = __shfl(pp1, sl + jj);
                unsigned vA = hI[sA * 32u + c];
                acA = __hfma2(u2h2(vA), u2h2(pA), acA);
            }
        }

        // combine chains in f32
        float2 fA = __half22float2(acA);
        float2 fB = __half22float2(acB);
        float2 fC = __half22float2(acC);
        float2 fD = __half22float2(acD);
        float acc0 = (fA.x + fB.x) + (fC.x + fD.x) + self0;
        float acc1 = (fA.y + fB.y) + (fC.y + fD.y) + self1;

        // reduce denominators within the half-wave (xor <= 16 stays inside)
        s0 += __shfl_xor(s0, 16); s1 += __shfl_xor(s1, 16);
        s0 += __shfl_xor(s0, 8);  s1 += __shfl_xor(s1, 8);
        s0 += __shfl_xor(s0, 4);  s1 += __shfl_xor(s1, 4);
        s0 += __shfl_xor(s0, 2);  s1 += __shfl_xor(s1, 2);
        s0 += __shfl_xor(s0, 1);  s1 += __shfl_xor(s1, 1);
        s0 += p0s; s1 += p1s;

        if (valid) {
            out[(size_t)node * 64 + c]      = acc0 / s0 + bi0;
            out[(size_t)node * 64 + 32 + c] = acc1 / s1 + bi1;
        }
    }
}

extern "C" void kernel_launch(void* const* d_in, const int* in_sizes, int n_in,
                              void* d_out, int out_size, void* d_ws, size_t ws_size,
                              hipStream_t stream)
{
    const float* x       = (const float*)d_in[0];
    const int*   ei      = (const int*)d_in[1];
    const float* W       = (const float*)d_in[2];
    const float* att_src = (const float*)d_in[3];
    const float* att_dst = (const float*)d_in[4];
    const float* bias    = (const float*)d_in[5];
    float* out = (float*)d_out;

    char* ws = (char*)d_ws;
    size_t off = 0;
    auto alloc = [&](size_t bytes) -> void* {
        void* p = ws + off;
        off = (off + bytes + 511) & ~(size_t)511;
        return p;
    };
    unsigned int* hI  = (unsigned int*)alloc((size_t)N_NODES * 32 * 4);
    float*  as_ = (float*)alloc((size_t)N_NODES * 2 * 4);
    float*  ad_ = (float*)alloc((size_t)N_NODES * 2 * 4);
    int*    gcur = (int*)alloc((size_t)NBUK * 4);
    unsigned int* barr = (unsigned int*)alloc((size_t)NBUK * BCAP * 4);

    zero_gcur<<<1, 512, 0, stream>>>(gcur);
    fused_gp<<<P_BLOCKS + G_BLOCKS, 512, 0, stream>>>(
        ei, gcur, barr, x, W, att_src, att_dst, hI, as_, ad_);
    aggregate<<<NBUK * 4, 512, 0, stream>>>(hI, as_, ad_, gcur, barr, bias, out);
}